// Round 1
// baseline (412.648 us; speedup 1.0000x reference)
//
#include <hip/hip_runtime.h>

#define NE 8
#define HD 1024
#define ID 2816
#define TT 4096
#define BM 128
#define BN 128
#define BK 32
#define NTH 256
#define MAXMT (TT / BM + NE) /* 40 worst-case M-tiles over all experts */

typedef __attribute__((ext_vector_type(4))) float f32x4;
typedef __attribute__((ext_vector_type(8))) short s16x8;
typedef __attribute__((ext_vector_type(4))) short s16x4;

// fp32 -> bf16 round-to-nearest-even (bit pattern in low 16)
__device__ __forceinline__ unsigned int f2bf1(float f) {
  unsigned int u = __float_as_uint(f);
  return (u + 0x7fffu + ((u >> 16) & 1u)) >> 16;
}
__device__ __forceinline__ unsigned int f2bfpk(float lo, float hi) {
  return f2bf1(lo) | (f2bf1(hi) << 16);
}

// Map flat M-tile index -> (expert, row range). batch_sizes may be int64 or
// int32 depending on harness x64 config; sniff the layout (int64 LE => odd
// words zero). Only reads 32 bytes, safe under both dtypes.
__device__ __forceinline__ bool map_tile(const void* bsp, int mt, int& e,
                                         int& mstart, int& rowend) {
  const int* w = (const int*)bsp;
  bool is64 = (w[1] == 0) && (w[3] == 0) && (w[5] == 0) && (w[7] == 0) &&
              ((w[0] | w[2] | w[4] | w[6]) != 0);
  long long start = 0;
  int rem = mt;
  for (int i = 0; i < NE; ++i) {
    long long b = is64 ? ((const long long*)bsp)[i] : (long long)w[i];
    if (b < 0) b = 0;
    int tiles = (int)((b + BM - 1) / BM);
    if (rem < tiles) {
      long long m0 = start + (long long)rem * BM;
      long long me = start + b;
      if (m0 >= TT) return false;
      if (me > TT) me = TT;
      e = i; mstart = (int)m0; rowend = (int)me;
      return true;
    }
    rem -= tiles;
    start += b;
  }
  return false;
}

// ---------------- Kernel 1: up = silu(x@w1[e]) * (x@w3[e]) ----------------
// A tile: [BM][BK] bf16 in LDS, 80B row stride (pad) -> b128 frag reads.
// B tiles: transposed [BN][BK] bf16, 72B row stride -> 2xb64 frag reads.
__global__ __launch_bounds__(NTH, 2) void moe_gemm1(
    const float* __restrict__ x, const float* __restrict__ w1,
    const float* __restrict__ w3, const void* __restrict__ bsp,
    unsigned short* __restrict__ up) {
  __shared__ __align__(16) char As[BM * 80];
  __shared__ __align__(16) char B1s[BN * 72];
  __shared__ __align__(16) char B3s[BN * 72];

  const int NT = ID / BN;  // 22
  int mt = blockIdx.x / NT;
  int nt = blockIdx.x - mt * NT;
  int e, mstart, rowend;
  if (!map_tile(bsp, mt, e, mstart, rowend)) return;
  const int n0 = nt * BN;
  const int tid = threadIdx.x;

  const float* w1e = w1 + (size_t)e * HD * ID;
  const float* w3e = w3 + (size_t)e * HD * ID;

  f32x4 acc1[4][4], acc3[4][4];
#pragma unroll
  for (int i = 0; i < 4; ++i)
#pragma unroll
    for (int j = 0; j < 4; ++j) { acc1[i][j] = (f32x4)0.f; acc3[i][j] = (f32x4)0.f; }

  const int lane = tid & 63;
  const int wv = tid >> 6;
  const int wr = wv >> 1, wc = wv & 1;
  const int q = lane >> 4;    // k-group 0..3
  const int r16 = lane & 15;

  const int a_k4 = (tid & 7) * 4;  // A stage: float4 k-offset
  const int a_row0 = tid >> 3;     // 0..31
  const int b_n = tid & 127;       // B stage: column
  const int b_kp0 = tid >> 7;      // 0..1
  const int gnB = n0 + b_n;

  for (int kt = 0; kt < HD / BK; ++kt) {
    const int kb = kt * BK;
    __syncthreads();
    // ---- stage A (x tile), coalesced float4 + cvt + b64 LDS write
#pragma unroll
    for (int it = 0; it < 4; ++it) {
      int r = a_row0 + it * 32;
      int gm = mstart + r;
      f32x4 v = (f32x4)0.f;
      if (gm < rowend) v = *(const f32x4*)(x + (size_t)gm * HD + kb + a_k4);
      unsigned long long p =
          (unsigned long long)f2bfpk(v[0], v[1]) |
          ((unsigned long long)f2bfpk(v[2], v[3]) << 32);
      *(unsigned long long*)(As + r * 80 + a_k4 * 2) = p;
    }
    // ---- stage B1/B3 transposed: column-pair strided loads (coalesced
    // across 64 consecutive n per instruction) -> packed b32 writes
#pragma unroll
    for (int kp = 0; kp < 8; ++kp) {
      int kpp = b_kp0 + kp * 2;
      int k = kb + kpp * 2;
      const float* p1 = w1e + (size_t)k * ID + gnB;
      *(unsigned int*)(B1s + b_n * 72 + kpp * 4) = f2bfpk(p1[0], p1[ID]);
      const float* p3 = w3e + (size_t)k * ID + gnB;
      *(unsigned int*)(B3s + b_n * 72 + kpp * 4) = f2bfpk(p3[0], p3[ID]);
    }
    __syncthreads();
    // ---- fragments + MFMA
    s16x8 a[4], b1[4], b3[4];
#pragma unroll
    for (int i = 0; i < 4; ++i)
      a[i] = *(const s16x8*)(As + (wr * 64 + i * 16 + r16) * 80 + q * 16);
#pragma unroll
    for (int j = 0; j < 4; ++j) {
      const char* pB1 = B1s + (wc * 64 + j * 16 + r16) * 72 + q * 16;
      s16x4 l1 = *(const s16x4*)(pB1);
      s16x4 h1 = *(const s16x4*)(pB1 + 8);
      b1[j] = __builtin_shufflevector(l1, h1, 0, 1, 2, 3, 4, 5, 6, 7);
      const char* pB3 = B3s + (wc * 64 + j * 16 + r16) * 72 + q * 16;
      s16x4 l3 = *(const s16x4*)(pB3);
      s16x4 h3 = *(const s16x4*)(pB3 + 8);
      b3[j] = __builtin_shufflevector(l3, h3, 0, 1, 2, 3, 4, 5, 6, 7);
    }
#pragma unroll
    for (int i = 0; i < 4; ++i)
#pragma unroll
      for (int j = 0; j < 4; ++j) {
        acc1[i][j] = __builtin_amdgcn_mfma_f32_16x16x32_bf16(a[i], b1[j], acc1[i][j], 0, 0, 0);
        acc3[i][j] = __builtin_amdgcn_mfma_f32_16x16x32_bf16(a[i], b3[j], acc3[i][j], 0, 0, 0);
      }
  }
  // ---- epilogue: silu(acc1)*acc3 -> bf16 up
#pragma unroll
  for (int i = 0; i < 4; ++i) {
#pragma unroll
    for (int r = 0; r < 4; ++r) {
      int gm = mstart + wr * 64 + i * 16 + q * 4 + r;
      if (gm < rowend) {
#pragma unroll
        for (int j = 0; j < 4; ++j) {
          float v1 = acc1[i][j][r];
          float v3 = acc3[i][j][r];
          float s = v1 / (1.f + __expf(-v1));
          float u = s * v3;
          int gn = n0 + wc * 64 + j * 16 + r16;
          up[(size_t)gm * ID + gn] = (unsigned short)f2bf1(u);
        }
      }
    }
  }
}

// ---------------- Kernel 2: out = up @ w2[e] ----------------
__global__ __launch_bounds__(NTH, 2) void moe_gemm2(
    const unsigned short* __restrict__ up, const float* __restrict__ w2,
    const void* __restrict__ bsp, float* __restrict__ out) {
  __shared__ __align__(16) char As[BM * 80];
  __shared__ __align__(16) char Bs[BN * 72];

  const int NT = HD / BN;  // 8
  int mt = blockIdx.x / NT;
  int nt = blockIdx.x - mt * NT;
  int e, mstart, rowend;
  if (!map_tile(bsp, mt, e, mstart, rowend)) return;
  const int n0 = nt * BN;
  const int tid = threadIdx.x;
  const float* w2e = w2 + (size_t)e * ID * HD;

  f32x4 acc[4][4];
#pragma unroll
  for (int i = 0; i < 4; ++i)
#pragma unroll
    for (int j = 0; j < 4; ++j) acc[i][j] = (f32x4)0.f;

  const int lane = tid & 63;
  const int wv = tid >> 6;
  const int wr = wv >> 1, wc = wv & 1;
  const int q = lane >> 4;
  const int r16 = lane & 15;

  const int a_k8 = (tid & 3) * 8;  // A stage: 8 bf16 (16B)
  const int a_row0 = tid >> 2;     // 0..63
  const int b_n = tid & 127;
  const int b_kp0 = tid >> 7;
  const int gnB = n0 + b_n;

  for (int kt = 0; kt < ID / BK; ++kt) {  // 88 steps
    const int kb = kt * BK;
    __syncthreads();
    // ---- stage A (up tile, already bf16): b128 load -> b128 LDS write
#pragma unroll
    for (int it = 0; it < 2; ++it) {
      int r = a_row0 + it * 64;
      int gm = mstart + r;
      s16x8 v = (s16x8)0;
      if (gm < rowend) v = *(const s16x8*)(up + (size_t)gm * ID + kb + a_k8);
      *(s16x8*)(As + r * 80 + a_k8 * 2) = v;
    }
    // ---- stage B (w2) transposed, column-pair loads
#pragma unroll
    for (int kp = 0; kp < 8; ++kp) {
      int kpp = b_kp0 + kp * 2;
      int k = kb + kpp * 2;
      const float* p = w2e + (size_t)k * HD + gnB;
      *(unsigned int*)(Bs + b_n * 72 + kpp * 4) = f2bfpk(p[0], p[HD]);
    }
    __syncthreads();
    s16x8 a[4], b[4];
#pragma unroll
    for (int i = 0; i < 4; ++i)
      a[i] = *(const s16x8*)(As + (wr * 64 + i * 16 + r16) * 80 + q * 16);
#pragma unroll
    for (int j = 0; j < 4; ++j) {
      const char* pB = Bs + (wc * 64 + j * 16 + r16) * 72 + q * 16;
      s16x4 lo = *(const s16x4*)(pB);
      s16x4 hi = *(const s16x4*)(pB + 8);
      b[j] = __builtin_shufflevector(lo, hi, 0, 1, 2, 3, 4, 5, 6, 7);
    }
#pragma unroll
    for (int i = 0; i < 4; ++i)
#pragma unroll
      for (int j = 0; j < 4; ++j)
        acc[i][j] = __builtin_amdgcn_mfma_f32_16x16x32_bf16(a[i], b[j], acc[i][j], 0, 0, 0);
  }
  // ---- epilogue: f32 store
#pragma unroll
  for (int i = 0; i < 4; ++i) {
#pragma unroll
    for (int r = 0; r < 4; ++r) {
      int gm = mstart + wr * 64 + i * 16 + q * 4 + r;
      if (gm < rowend) {
#pragma unroll
        for (int j = 0; j < 4; ++j) {
          int gn = n0 + wc * 64 + j * 16 + r16;
          out[(size_t)gm * HD + gn] = acc[i][j][r];
        }
      }
    }
  }
}

extern "C" void kernel_launch(void* const* d_in, const int* in_sizes, int n_in,
                              void* d_out, int out_size, void* d_ws, size_t ws_size,
                              hipStream_t stream) {
  const float* x = (const float*)d_in[0];
  const float* w1 = (const float*)d_in[1];
  const float* w2 = (const float*)d_in[2];
  const float* w3 = (const float*)d_in[3];
  const void* bs = d_in[4];
  float* out = (float*)d_out;
  unsigned short* up = (unsigned short*)d_ws;  // [TT][ID] bf16, ~23 MB

  // zero output: rows not owned by any expert must be 0 (d_out is poisoned)
  hipMemsetAsync(d_out, 0, (size_t)out_size * sizeof(float), stream);

  dim3 blk(NTH);
  moe_gemm1<<<dim3(MAXMT * (ID / BN)), blk, 0, stream>>>(x, w1, w3, bs, up);
  moe_gemm2<<<dim3(MAXMT * (HD / BN)), blk, 0, stream>>>(up, w2, bs, out);
}

// Round 2
// 215.633 us; speedup vs baseline: 1.9137x; 1.9137x over previous
//
#include <hip/hip_runtime.h>
#include <hip/hip_bf16.h>

#define NE 8
#define HD 1024
#define ID 2816
#define TT 4096
#define BM 128
#define BK 32
#define BN1 64
#define BN2 64
#define NTH 256
#define MAXMT (TT / BM + NE) /* 40 worst-case M-tiles */

typedef __attribute__((ext_vector_type(4))) float f32x4;
typedef __attribute__((ext_vector_type(8))) short s16x8;
typedef __attribute__((ext_vector_type(4))) short s16x4;

// fp32x2 -> packed bf16x2 (RNE, hardware v_cvt_pk_bf16_f32 via HIP intrinsic)
__device__ __forceinline__ unsigned int f2bfpk(float lo, float hi) {
  float2 t; t.x = lo; t.y = hi;
  union { __hip_bfloat162 h2; unsigned int u; } cv;
  cv.h2 = __float22bfloat162_rn(t);
  return cv.u;
}

// Map flat M-tile index -> (expert, row range). batch_sizes may be int64 or
// int32; sniff layout (int64 LE => odd words zero).
__device__ __forceinline__ bool map_tile(const void* bsp, int mt, int& e,
                                         int& mstart, int& rowend) {
  const int* w = (const int*)bsp;
  bool is64 = (w[1] == 0) && (w[3] == 0) && (w[5] == 0) && (w[7] == 0) &&
              ((w[0] | w[2] | w[4] | w[6]) != 0);
  long long start = 0;
  int rem = mt;
  for (int i = 0; i < NE; ++i) {
    long long b = is64 ? ((const long long*)bsp)[i] : (long long)w[i];
    if (b < 0) b = 0;
    int tiles = (int)((b + BM - 1) / BM);
    if (rem < tiles) {
      long long m0 = start + (long long)rem * BM;
      long long me = start + b;
      if (m0 >= TT) return false;
      if (me > TT) me = TT;
      e = i; mstart = (int)m0; rowend = (int)me;
      return true;
    }
    rem -= tiles;
    start += b;
  }
  return false;
}

// ---------------- Kernel 1: up = silu(x@w1[e]) * (x@w3[e]) ----------------
// BM=128 x BN1=64, BK=32, 4 waves (2Mx2N, 64x32/wave), dual accumulators.
// Double-buffered LDS + register prefetch: 1 barrier per k-step.
__global__ __launch_bounds__(NTH, 2) void moe_gemm1(
    const float* __restrict__ x, const float* __restrict__ w1,
    const float* __restrict__ w3, const void* __restrict__ bsp,
    __hip_bfloat16* __restrict__ up) {
  __shared__ __align__(16) char As[2][BM * 80];
  __shared__ __align__(16) char B1s[2][BN1 * 72];
  __shared__ __align__(16) char B3s[2][BN1 * 72];

  // XCD chunk swizzle (grid 1760 % 8 == 0) + mt-inner logical order:
  // consecutive logical blocks share the weight slab and co-reside per XCD.
  const int NWG = (ID / BN1) * MAXMT;  // 44*40 = 1760
  int bid = blockIdx.x;
  int logical = (bid & 7) * (NWG >> 3) + (bid >> 3);
  int mt = logical % MAXMT;
  int nt = logical / MAXMT;
  int e, mstart, rowend;
  if (!map_tile(bsp, mt, e, mstart, rowend)) return;
  const int n0 = nt * BN1;
  const int tid = threadIdx.x;

  const int lane = tid & 63;
  const int wv = tid >> 6;
  const int wr = wv >> 1, wc = wv & 1;
  const int q = lane >> 4, r16 = lane & 15;

  // staging geometry
  const int a_k4 = (tid & 7) * 4;   // float4 k-offset within BK
  const int a_r0 = tid >> 3;        // 0..31 (4 rows, stride 32)
  const int b_n = tid & 63;         // B column
  const int b_kp0 = tid >> 6;       // 0..3 (4 k-pairs, stride 4)

  const float* w1p = w1 + (size_t)e * HD * ID + n0 + b_n;
  const float* w3p = w3 + (size_t)e * HD * ID + n0 + b_n;

  f32x4 acc1[4][2], acc3[4][2];
#pragma unroll
  for (int i = 0; i < 4; ++i)
#pragma unroll
    for (int j = 0; j < 2; ++j) { acc1[i][j] = (f32x4)0.f; acc3[i][j] = (f32x4)0.f; }

  // prefetch registers
  f32x4 xa[4];
  float wa1[4][2], wa3[4][2];

  auto load_tile = [&](int kb) {
#pragma unroll
    for (int it = 0; it < 4; ++it) {
      int gm = mstart + a_r0 + it * 32;
      f32x4 v = (f32x4)0.f;
      if (gm < rowend) v = *(const f32x4*)(x + (size_t)gm * HD + kb + a_k4);
      xa[it] = v;
    }
#pragma unroll
    for (int i = 0; i < 4; ++i) {
      int k = kb + 2 * (b_kp0 + i * 4);
      const float* p1 = w1p + (size_t)k * ID;
      wa1[i][0] = p1[0]; wa1[i][1] = p1[ID];
      const float* p3 = w3p + (size_t)k * ID;
      wa3[i][0] = p3[0]; wa3[i][1] = p3[ID];
    }
  };
  auto store_tile = [&](int buf) {
#pragma unroll
    for (int it = 0; it < 4; ++it) {
      int r = a_r0 + it * 32;
      unsigned long long p =
          (unsigned long long)f2bfpk(xa[it][0], xa[it][1]) |
          ((unsigned long long)f2bfpk(xa[it][2], xa[it][3]) << 32);
      *(unsigned long long*)(As[buf] + r * 80 + a_k4 * 2) = p;
    }
#pragma unroll
    for (int i = 0; i < 4; ++i) {
      int kp = b_kp0 + i * 4;
      *(unsigned int*)(B1s[buf] + b_n * 72 + kp * 4) = f2bfpk(wa1[i][0], wa1[i][1]);
      *(unsigned int*)(B3s[buf] + b_n * 72 + kp * 4) = f2bfpk(wa3[i][0], wa3[i][1]);
    }
  };
  auto compute = [&](int buf) {
    s16x8 a[4], b1[2], b3[2];
#pragma unroll
    for (int i = 0; i < 4; ++i)
      a[i] = *(const s16x8*)(As[buf] + (wr * 64 + i * 16 + r16) * 80 + q * 16);
#pragma unroll
    for (int j = 0; j < 2; ++j) {
      const char* p1 = B1s[buf] + (wc * 32 + j * 16 + r16) * 72 + q * 16;
      s16x4 l1 = *(const s16x4*)p1, h1 = *(const s16x4*)(p1 + 8);
      b1[j] = __builtin_shufflevector(l1, h1, 0, 1, 2, 3, 4, 5, 6, 7);
      const char* p3 = B3s[buf] + (wc * 32 + j * 16 + r16) * 72 + q * 16;
      s16x4 l3 = *(const s16x4*)p3, h3 = *(const s16x4*)(p3 + 8);
      b3[j] = __builtin_shufflevector(l3, h3, 0, 1, 2, 3, 4, 5, 6, 7);
    }
#pragma unroll
    for (int i = 0; i < 4; ++i)
#pragma unroll
      for (int j = 0; j < 2; ++j) {
        acc1[i][j] = __builtin_amdgcn_mfma_f32_16x16x32_bf16(a[i], b1[j], acc1[i][j], 0, 0, 0);
        acc3[i][j] = __builtin_amdgcn_mfma_f32_16x16x32_bf16(a[i], b3[j], acc3[i][j], 0, 0, 0);
      }
  };

  const int NK = HD / BK;  // 32
  load_tile(0);
  store_tile(0);
  for (int kt = 0; kt < NK; ++kt) {
    __syncthreads();  // buf[kt&1] ready; prior reads of buf[(kt+1)&1] drained
    if (kt + 1 < NK) load_tile((kt + 1) * BK);  // globals in flight under MFMA
    compute(kt & 1);
    if (kt + 1 < NK) store_tile((kt + 1) & 1);  // waits vmcnt, cvt, ds_write
  }

  // epilogue: silu(acc1)*acc3 -> bf16
#pragma unroll
  for (int i = 0; i < 4; ++i)
#pragma unroll
    for (int r = 0; r < 4; ++r) {
      int gm = mstart + wr * 64 + i * 16 + q * 4 + r;
      if (gm < rowend) {
#pragma unroll
        for (int j = 0; j < 2; ++j) {
          float v1 = acc1[i][j][r], v3 = acc3[i][j][r];
          float s = v1 / (1.f + __expf(-v1));
          up[(size_t)gm * ID + n0 + wc * 32 + j * 16 + r16] = __float2bfloat16(s * v3);
        }
      }
    }
}

// ---------------- Kernel 2: out = up @ w2[e] ----------------
__global__ __launch_bounds__(NTH, 2) void moe_gemm2(
    const __hip_bfloat16* __restrict__ up, const float* __restrict__ w2,
    const void* __restrict__ bsp, float* __restrict__ out) {
  __shared__ __align__(16) char As[2][BM * 80];
  __shared__ __align__(16) char Bs[2][BN2 * 72];

  const int NWG = (HD / BN2) * MAXMT;  // 16*40 = 640
  int bid = blockIdx.x;
  int logical = (bid & 7) * (NWG >> 3) + (bid >> 3);
  int mt = logical % MAXMT;
  int nt = logical / MAXMT;
  int e, mstart, rowend;
  if (!map_tile(bsp, mt, e, mstart, rowend)) return;
  const int n0 = nt * BN2;
  const int tid = threadIdx.x;

  const int lane = tid & 63;
  const int wv = tid >> 6;
  const int wr = wv >> 1, wc = wv & 1;
  const int q = lane >> 4, r16 = lane & 15;

  const int a_k8 = (tid & 3) * 8;   // 8 bf16 (16B) k-offset
  const int a_r0 = tid >> 2;        // 0..63 (2 rows, stride 64)
  const int b_n = tid & 63;
  const int b_kp0 = tid >> 6;

  const float* w2p = w2 + (size_t)e * ID * HD + n0 + b_n;

  f32x4 acc[4][2];
#pragma unroll
  for (int i = 0; i < 4; ++i)
#pragma unroll
    for (int j = 0; j < 2; ++j) acc[i][j] = (f32x4)0.f;

  s16x8 ua[2];
  float wa[4][2];

  auto load_tile = [&](int kb) {
#pragma unroll
    for (int it = 0; it < 2; ++it) {
      int gm = mstart + a_r0 + it * 64;
      s16x8 v = (s16x8)0;
      if (gm < rowend) v = *(const s16x8*)(up + (size_t)gm * ID + kb + a_k8);
      ua[it] = v;
    }
#pragma unroll
    for (int i = 0; i < 4; ++i) {
      int k = kb + 2 * (b_kp0 + i * 4);
      const float* p = w2p + (size_t)k * HD;
      wa[i][0] = p[0]; wa[i][1] = p[HD];
    }
  };
  auto store_tile = [&](int buf) {
#pragma unroll
    for (int it = 0; it < 2; ++it) {
      int r = a_r0 + it * 64;
      *(s16x8*)(As[buf] + r * 80 + a_k8 * 2) = ua[it];
    }
#pragma unroll
    for (int i = 0; i < 4; ++i) {
      int kp = b_kp0 + i * 4;
      *(unsigned int*)(Bs[buf] + b_n * 72 + kp * 4) = f2bfpk(wa[i][0], wa[i][1]);
    }
  };
  auto compute = [&](int buf) {
    s16x8 a[4], b[2];
#pragma unroll
    for (int i = 0; i < 4; ++i)
      a[i] = *(const s16x8*)(As[buf] + (wr * 64 + i * 16 + r16) * 80 + q * 16);
#pragma unroll
    for (int j = 0; j < 2; ++j) {
      const char* p = Bs[buf] + (wc * 32 + j * 16 + r16) * 72 + q * 16;
      s16x4 lo = *(const s16x4*)p, hi = *(const s16x4*)(p + 8);
      b[j] = __builtin_shufflevector(lo, hi, 0, 1, 2, 3, 4, 5, 6, 7);
    }
#pragma unroll
    for (int i = 0; i < 4; ++i)
#pragma unroll
      for (int j = 0; j < 2; ++j)
        acc[i][j] = __builtin_amdgcn_mfma_f32_16x16x32_bf16(a[i], b[j], acc[i][j], 0, 0, 0);
  };

  const int NK = ID / BK;  // 88
  load_tile(0);
  store_tile(0);
  for (int kt = 0; kt < NK; ++kt) {
    __syncthreads();
    if (kt + 1 < NK) load_tile((kt + 1) * BK);
    compute(kt & 1);
    if (kt + 1 < NK) store_tile((kt + 1) & 1);
  }

#pragma unroll
  for (int i = 0; i < 4; ++i)
#pragma unroll
    for (int r = 0; r < 4; ++r) {
      int gm = mstart + wr * 64 + i * 16 + q * 4 + r;
      if (gm < rowend) {
#pragma unroll
        for (int j = 0; j < 2; ++j)
          out[(size_t)gm * HD + n0 + wc * 32 + j * 16 + r16] = acc[i][j][r];
      }
    }
}

extern "C" void kernel_launch(void* const* d_in, const int* in_sizes, int n_in,
                              void* d_out, int out_size, void* d_ws, size_t ws_size,
                              hipStream_t stream) {
  const float* x = (const float*)d_in[0];
  const float* w1 = (const float*)d_in[1];
  const float* w2 = (const float*)d_in[2];
  const float* w3 = (const float*)d_in[3];
  const void* bs = d_in[4];
  float* out = (float*)d_out;
  __hip_bfloat16* up = (__hip_bfloat16*)d_ws;  // [TT][ID] bf16, ~23 MB

  hipMemsetAsync(d_out, 0, (size_t)out_size * sizeof(float), stream);

  dim3 blk(NTH);
  moe_gemm1<<<dim3((ID / BN1) * MAXMT), blk, 0, stream>>>(x, w1, w3, bs, up);
  moe_gemm2<<<dim3((HD / BN2) * MAXMT), blk, 0, stream>>>(up, w2, bs, out);
}

// Round 5
// 195.306 us; speedup vs baseline: 2.1128x; 1.1041x over previous
//
#include <hip/hip_runtime.h>
#include <hip/hip_bf16.h>

#define NE 8
#define HD 1024
#define ID 2816
#define TT 4096
#define BM 128
#define BK 32
#define BN1 64
#define BN2 64
#define NTH 256
#define MAXMT (TT / BM + NE) /* 40 worst-case M-tiles */

typedef __attribute__((ext_vector_type(4))) float f32x4;
typedef __attribute__((ext_vector_type(8))) short s16x8;
typedef __attribute__((ext_vector_type(4))) short s16x4;

// fp32x2 -> packed bf16x2 (RNE, v_cvt_pk_bf16_f32)
__device__ __forceinline__ unsigned int f2bfpk(float lo, float hi) {
  float2 t; t.x = lo; t.y = hi;
  union { __hip_bfloat162 h2; unsigned int u; } cv;
  cv.h2 = __float22bfloat162_rn(t);
  return cv.u;
}

// barrier that does NOT drain vmcnt: prefetch loads stay in flight
__device__ __forceinline__ void lds_barrier() {
  asm volatile("s_waitcnt lgkmcnt(0)" ::: "memory");
  __builtin_amdgcn_s_barrier();
}

__device__ __forceinline__ bool map_tile(const void* bsp, int mt, int& e,
                                         int& mstart, int& rowend) {
  const int* w = (const int*)bsp;
  bool is64 = (w[1] == 0) && (w[3] == 0) && (w[5] == 0) && (w[7] == 0) &&
              ((w[0] | w[2] | w[4] | w[6]) != 0);
  long long start = 0;
  int rem = mt;
  for (int i = 0; i < NE; ++i) {
    long long b = is64 ? ((const long long*)bsp)[i] : (long long)w[i];
    if (b < 0) b = 0;
    int tiles = (int)((b + BM - 1) / BM);
    if (rem < tiles) {
      long long m0 = start + (long long)rem * BM;
      long long me = start + b;
      if (m0 >= TT) return false;
      if (me > TT) me = TT;
      e = i; mstart = (int)m0; rowend = (int)me;
      return true;
    }
    rem -= tiles;
    start += b;
  }
  return false;
}

// ---------------- Kernel 0: x (fp32) -> xbf (bf16) ----------------
__global__ __launch_bounds__(NTH) void cvt_x(const float* __restrict__ x,
                                             __hip_bfloat16* __restrict__ xb) {
  size_t i = ((size_t)blockIdx.x * NTH + threadIdx.x) * 8;
  f32x4 v0 = *(const f32x4*)(x + i);
  f32x4 v1 = *(const f32x4*)(x + i + 4);
  s16x8 o;
  unsigned int p0 = f2bfpk(v0[0], v0[1]), p1 = f2bfpk(v0[2], v0[3]);
  unsigned int p2 = f2bfpk(v1[0], v1[1]), p3 = f2bfpk(v1[2], v1[3]);
  o[0] = (short)(p0 & 0xffff); o[1] = (short)(p0 >> 16);
  o[2] = (short)(p1 & 0xffff); o[3] = (short)(p1 >> 16);
  o[4] = (short)(p2 & 0xffff); o[5] = (short)(p2 >> 16);
  o[6] = (short)(p3 & 0xffff); o[7] = (short)(p3 >> 16);
  *(s16x8*)((unsigned short*)xb + i) = o;
}

// ---------------- Kernel 1: up = silu(x@w1[e]) * (x@w3[e]) ----------------
// BM=128 x BN1=64, BK=32, 4 waves. 2-deep prefetch: load k+2 / compute k /
// store k+1, one lds_barrier per k-step, loads cross one barrier in flight.
__global__ __launch_bounds__(NTH, 2) void moe_gemm1(
    const __hip_bfloat16* __restrict__ xbf, const float* __restrict__ w1,
    const float* __restrict__ w3, const void* __restrict__ bsp,
    __hip_bfloat16* __restrict__ up) {
  __shared__ __align__(16) char As[2][BM * 80];
  __shared__ __align__(16) char B1s[2][BN1 * 72];
  __shared__ __align__(16) char B3s[2][BN1 * 72];

  const int NWG = (ID / BN1) * MAXMT;  // 1760, %8==0
  int bid = blockIdx.x;
  int logical = (bid & 7) * (NWG >> 3) + (bid >> 3);
  int mt = logical % MAXMT;
  int nt = logical / MAXMT;
  int e, mstart, rowend;
  if (!map_tile(bsp, mt, e, mstart, rowend)) return;
  const int n0 = nt * BN1;
  const int tid = threadIdx.x;

  const int lane = tid & 63;
  const int wv = tid >> 6;
  const int wr = wv >> 1, wc = wv & 1;
  const int q = lane >> 4, r16 = lane & 15;

  // staging geometry
  const int a_k8 = (tid & 3) * 8;   // bf16 k-offset (8 elems = 16B)
  const int a_r0 = tid >> 2;        // 0..63, rows {a_r0, a_r0+64}
  const int b_n = tid & 63;
  const int b_kp0 = tid >> 6;       // 0..3

  const bool ok0 = (mstart + a_r0) < rowend;
  const bool ok1 = (mstart + a_r0 + 64) < rowend;

  // cursors (advance by fixed strides; offsets inside are compile-time)
  const __hip_bfloat16* xc = xbf + (size_t)(mstart + a_r0) * HD + a_k8;
  const float* w1c = w1 + (size_t)e * HD * ID + n0 + b_n + (size_t)(2 * b_kp0) * ID;
  const float* w3c = w3 + (size_t)e * HD * ID + n0 + b_n + (size_t)(2 * b_kp0) * ID;

  f32x4 acc1[4][2], acc3[4][2];
#pragma unroll
  for (int i = 0; i < 4; ++i)
#pragma unroll
    for (int j = 0; j < 2; ++j) { acc1[i][j] = (f32x4)0.f; acc3[i][j] = (f32x4)0.f; }

  // two register prefetch buffers (all statically indexed)
  s16x8 A0[2], A1[2];
  float W1a[4][2], W3a[4][2], W1b[4][2], W3b[4][2];

  auto load_t = [&](s16x8* A, float (*W1_)[2], float (*W3_)[2]) {
    A[0] = ok0 ? *(const s16x8*)xc : (s16x8)0;
    A[1] = ok1 ? *(const s16x8*)(xc + (size_t)64 * HD) : (s16x8)0;
    xc += BK;
#pragma unroll
    for (int i = 0; i < 4; ++i) {
      const float* p1 = w1c + (size_t)(8 * i) * ID;
      W1_[i][0] = p1[0]; W1_[i][1] = p1[ID];
      const float* p3 = w3c + (size_t)(8 * i) * ID;
      W3_[i][0] = p3[0]; W3_[i][1] = p3[ID];
    }
    w1c += (size_t)BK * ID; w3c += (size_t)BK * ID;
  };
  auto store_t = [&](char* As_, char* B1_, char* B3_, const s16x8* A,
                     const float (*W1_)[2], const float (*W3_)[2]) {
    *(s16x8*)(As_ + a_r0 * 80 + a_k8 * 2) = A[0];
    *(s16x8*)(As_ + (a_r0 + 64) * 80 + a_k8 * 2) = A[1];
#pragma unroll
    for (int i = 0; i < 4; ++i) {
      int kp = b_kp0 + i * 4;
      *(unsigned int*)(B1_ + b_n * 72 + kp * 4) = f2bfpk(W1_[i][0], W1_[i][1]);
      *(unsigned int*)(B3_ + b_n * 72 + kp * 4) = f2bfpk(W3_[i][0], W3_[i][1]);
    }
  };
  auto compute_t = [&](const char* As_, const char* B1_, const char* B3_) {
    s16x8 a[4], b1[2], b3[2];
#pragma unroll
    for (int i = 0; i < 4; ++i)
      a[i] = *(const s16x8*)(As_ + (wr * 64 + i * 16 + r16) * 80 + q * 16);
#pragma unroll
    for (int j = 0; j < 2; ++j) {
      const char* p1 = B1_ + (wc * 32 + j * 16 + r16) * 72 + q * 16;
      s16x4 l1 = *(const s16x4*)p1, h1 = *(const s16x4*)(p1 + 8);
      b1[j] = __builtin_shufflevector(l1, h1, 0, 1, 2, 3, 4, 5, 6, 7);
      const char* p3 = B3_ + (wc * 32 + j * 16 + r16) * 72 + q * 16;
      s16x4 l3 = *(const s16x4*)p3, h3 = *(const s16x4*)(p3 + 8);
      b3[j] = __builtin_shufflevector(l3, h3, 0, 1, 2, 3, 4, 5, 6, 7);
    }
#pragma unroll
    for (int i = 0; i < 4; ++i)
#pragma unroll
      for (int j = 0; j < 2; ++j) {
        acc1[i][j] = __builtin_amdgcn_mfma_f32_16x16x32_bf16(a[i], b1[j], acc1[i][j], 0, 0, 0);
        acc3[i][j] = __builtin_amdgcn_mfma_f32_16x16x32_bf16(a[i], b3[j], acc3[i][j], 0, 0, 0);
      }
  };

  const int NK = HD / BK;  // 32 (even)
  load_t(A0, W1a, W3a);            // tile 0
  load_t(A1, W1b, W3b);            // tile 1
  store_t(As[0], B1s[0], B3s[0], A0, W1a, W3a);
  lds_barrier();
  for (int kt = 0; kt < NK; kt += 2) {
    // phase A: compute tile kt (lds0); store tile kt+1; load tile kt+2
    if (kt + 2 < NK) load_t(A0, W1a, W3a);
    compute_t(As[0], B1s[0], B3s[0]);
    store_t(As[1], B1s[1], B3s[1], A1, W1b, W3b);
    lds_barrier();
    // phase B: compute tile kt+1 (lds1); store tile kt+2; load tile kt+3
    if (kt + 3 < NK) load_t(A1, W1b, W3b);
    compute_t(As[1], B1s[1], B3s[1]);
    if (kt + 2 < NK) {
      store_t(As[0], B1s[0], B3s[0], A0, W1a, W3a);
      lds_barrier();
    }
  }

  // epilogue: silu(acc1)*acc3 -> bf16
#pragma unroll
  for (int i = 0; i < 4; ++i)
#pragma unroll
    for (int r = 0; r < 4; ++r) {
      int gm = mstart + wr * 64 + i * 16 + q * 4 + r;
      if (gm < rowend) {
#pragma unroll
        for (int j = 0; j < 2; ++j) {
          float v1 = acc1[i][j][r], v3 = acc3[i][j][r];
          float s = v1 / (1.f + __expf(-v1));
          up[(size_t)gm * ID + n0 + wc * 32 + j * 16 + r16] = __float2bfloat16(s * v3);
        }
      }
    }
}

// ---------------- Kernel 2: out = up @ w2[e] ----------------
__global__ __launch_bounds__(NTH, 2) void moe_gemm2(
    const __hip_bfloat16* __restrict__ up, const float* __restrict__ w2,
    const void* __restrict__ bsp, float* __restrict__ out) {
  __shared__ __align__(16) char As[2][BM * 80];
  __shared__ __align__(16) char Bs[2][BN2 * 72];

  const int NWG = (HD / BN2) * MAXMT;  // 640, %8==0
  int bid = blockIdx.x;
  int logical = (bid & 7) * (NWG >> 3) + (bid >> 3);
  int mt = logical % MAXMT;
  int nt = logical / MAXMT;
  int e, mstart, rowend;
  if (!map_tile(bsp, mt, e, mstart, rowend)) return;
  const int n0 = nt * BN2;
  const int tid = threadIdx.x;

  const int lane = tid & 63;
  const int wv = tid >> 6;
  const int wr = wv >> 1, wc = wv & 1;
  const int q = lane >> 4, r16 = lane & 15;

  const int a_k8 = (tid & 3) * 8;
  const int a_r0 = tid >> 2;
  const int b_n = tid & 63;
  const int b_kp0 = tid >> 6;

  const bool ok0 = (mstart + a_r0) < rowend;
  const bool ok1 = (mstart + a_r0 + 64) < rowend;

  const __hip_bfloat16* uc = up + (size_t)(mstart + a_r0) * ID + a_k8;
  const float* w2c = w2 + (size_t)e * ID * HD + n0 + b_n + (size_t)(2 * b_kp0) * HD;

  f32x4 acc[4][2];
#pragma unroll
  for (int i = 0; i < 4; ++i)
#pragma unroll
    for (int j = 0; j < 2; ++j) acc[i][j] = (f32x4)0.f;

  s16x8 A0[2], A1[2];
  float Wa[4][2], Wb[4][2];

  auto load_t = [&](s16x8* A, float (*W_)[2]) {
    A[0] = ok0 ? *(const s16x8*)uc : (s16x8)0;
    A[1] = ok1 ? *(const s16x8*)(uc + (size_t)64 * ID) : (s16x8)0;
    uc += BK;
#pragma unroll
    for (int i = 0; i < 4; ++i) {
      const float* p = w2c + (size_t)(8 * i) * HD;
      W_[i][0] = p[0]; W_[i][1] = p[HD];
    }
    w2c += (size_t)BK * HD;
  };
  auto store_t = [&](char* As_, char* B_, const s16x8* A, const float (*W_)[2]) {
    *(s16x8*)(As_ + a_r0 * 80 + a_k8 * 2) = A[0];
    *(s16x8*)(As_ + (a_r0 + 64) * 80 + a_k8 * 2) = A[1];
#pragma unroll
    for (int i = 0; i < 4; ++i) {
      int kp = b_kp0 + i * 4;
      *(unsigned int*)(B_ + b_n * 72 + kp * 4) = f2bfpk(W_[i][0], W_[i][1]);
    }
  };
  auto compute_t = [&](const char* As_, const char* B_) {
    s16x8 a[4], b[2];
#pragma unroll
    for (int i = 0; i < 4; ++i)
      a[i] = *(const s16x8*)(As_ + (wr * 64 + i * 16 + r16) * 80 + q * 16);
#pragma unroll
    for (int j = 0; j < 2; ++j) {
      const char* p = B_ + (wc * 32 + j * 16 + r16) * 72 + q * 16;
      s16x4 lo = *(const s16x4*)p, hi = *(const s16x4*)(p + 8);
      b[j] = __builtin_shufflevector(lo, hi, 0, 1, 2, 3, 4, 5, 6, 7);
    }
#pragma unroll
    for (int i = 0; i < 4; ++i)
#pragma unroll
      for (int j = 0; j < 2; ++j)
        acc[i][j] = __builtin_amdgcn_mfma_f32_16x16x32_bf16(a[i], b[j], acc[i][j], 0, 0, 0);
  };

  const int NK = ID / BK;  // 88 (even)
  load_t(A0, Wa);
  load_t(A1, Wb);
  store_t(As[0], Bs[0], A0, Wa);
  lds_barrier();
  for (int kt = 0; kt < NK; kt += 2) {
    if (kt + 2 < NK) load_t(A0, Wa);
    compute_t(As[0], Bs[0]);
    store_t(As[1], Bs[1], A1, Wb);
    lds_barrier();
    if (kt + 3 < NK) load_t(A1, Wb);
    compute_t(As[1], Bs[1]);
    if (kt + 2 < NK) {
      store_t(As[0], Bs[0], A0, Wa);
      lds_barrier();
    }
  }

#pragma unroll
  for (int i = 0; i < 4; ++i)
#pragma unroll
    for (int r = 0; r < 4; ++r) {
      int gm = mstart + wr * 64 + i * 16 + q * 4 + r;
      if (gm < rowend) {
#pragma unroll
        for (int j = 0; j < 2; ++j)
          out[(size_t)gm * HD + n0 + wc * 32 + j * 16 + r16] = acc[i][j][r];
      }
    }
}

extern "C" void kernel_launch(void* const* d_in, const int* in_sizes, int n_in,
                              void* d_out, int out_size, void* d_ws, size_t ws_size,
                              hipStream_t stream) {
  const float* x = (const float*)d_in[0];
  const float* w1 = (const float*)d_in[1];
  const float* w2 = (const float*)d_in[2];
  const float* w3 = (const float*)d_in[3];
  const void* bs = d_in[4];
  float* out = (float*)d_out;
  // ws layout: xbf [TT*HD bf16 = 8.39 MB] | up [TT*ID bf16 = 23.1 MB]
  __hip_bfloat16* xbf = (__hip_bfloat16*)d_ws;
  __hip_bfloat16* up = (__hip_bfloat16*)((char*)d_ws + (size_t)TT * HD * 2);

  hipMemsetAsync(d_out, 0, (size_t)out_size * sizeof(float), stream);

  dim3 blk(NTH);
  cvt_x<<<dim3(TT * HD / (8 * NTH)), blk, 0, stream>>>(x, xbf);
  moe_gemm1<<<dim3((ID / BN1) * MAXMT), blk, 0, stream>>>(xbf, w1, w3, bs, up);
  moe_gemm2<<<dim3((HD / BN2) * MAXMT), blk, 0, stream>>>(up, w2, bs, out);
}